// Round 5
// baseline (708.242 us; speedup 1.0000x reference)
//
#include <hip/hip_runtime.h>

// ShiftWise conv, register-sliding-window + software-pipelined version.
// lora1 = 15x3 conv, lora2 = 3x15 conv, small = 3x3 conv (i=2), each BN'd
// with batch stats, + rep_x residual; ghost channels copied through.
// Pass1: per-(c,u) sum/sumsq of the three conv outputs.
// Reduce: fold stats into (A1,A2,A3,K). Pass2: recompute convs, write
// y = A1*l1 + A2*l2 + A3*s + K + x.
//
// Block = 256 threads = 16 batches x 14 col strips (+32 inactive lanes,
// 'act'-guarded). Each thread: 8-row x 4-col output strip, walks input rows
// with a DOUBLE-BUFFERED 20-float register window (prefetch row s+1 before
// computing row s -> vmcnt(5) not vmcnt(0)). Weights uniform per block ->
// SGPRs. launch_bounds(256,3): 12 waves/CU exact granularity.

#define B_    32
#define CIN   256
#define REPN  196
#define HW    56
#define IMG   3136
#define NTOT  (B_ * CIN * IMG)
#define NCONVBLK 2800   // 25 c-groups x (8 c x 14 u); u = rb*2+bh
#define NGHOSTBLK 1920  // 60 ghost channels * 32 batches

__device__ __forceinline__ void load_row20(float (&w)[20], const float* __restrict__ in,
                                           int base) {
  // i0,i1 can under-run only at the very first image; i3,i4 can over-run only
  // at the very last. i2 is provably in-bounds for active threads.
  int i0 = base;      i0 = i0 < 0 ? 0 : i0;
  int i1 = base + 4;  i1 = i1 < 0 ? 0 : i1;
  int i3 = base + 12; i3 = i3 > (NTOT - 4) ? (NTOT - 4) : i3;
  int i4 = base + 16; i4 = i4 > (NTOT - 4) ? (NTOT - 4) : i4;
  const float4 v0 = *reinterpret_cast<const float4*>(in + i0);
  const float4 v1 = *reinterpret_cast<const float4*>(in + i1);
  const float4 v2 = *reinterpret_cast<const float4*>(in + base + 8);
  const float4 v3 = *reinterpret_cast<const float4*>(in + i3);
  const float4 v4 = *reinterpret_cast<const float4*>(in + i4);
  w[0]=v0.x;  w[1]=v0.y;  w[2]=v0.z;  w[3]=v0.w;
  w[4]=v1.x;  w[5]=v1.y;  w[6]=v1.z;  w[7]=v1.w;
  w[8]=v2.x;  w[9]=v2.y;  w[10]=v2.z; w[11]=v2.w;
  w[12]=v3.x; w[13]=v3.y; w[14]=v3.z; w[15]=v3.w;
  w[16]=v4.x; w[17]=v4.y; w[18]=v4.z; w[19]=v4.w;
}

template <bool PASS2>
__launch_bounds__(256, 3)
__global__ void sw_conv(const float* __restrict__ in, const int* __restrict__ rep_idx,
                        const int* __restrict__ ghost_idx, const float* __restrict__ wsum,
                        const float* __restrict__ stats2, float* __restrict__ partial,
                        float* __restrict__ out) {
  const int bid = blockIdx.x;
  const int tid = threadIdx.x;

  if (PASS2 && bid >= NCONVBLK) {  // ghost channel copy
    const int g = bid - NCONVBLK;
    const int j = g >> 5, b = g & 31;
    const int src_c = ghost_idx[j];
    const float4* s = reinterpret_cast<const float4*>(in + (size_t)(b * CIN + src_c) * IMG);
    float4* d = reinterpret_cast<float4*>(out + ((size_t)(b * CIN) + REPN + j) * IMG);
    #pragma unroll 1
    for (int i = tid; i < 784; i += 256) d[i] = s[i];
    return;
  }

  // XCD swizzle: all 14 u-blocks of channel c share bid mod 8 -> same XCD L2.
  const int c = (bid / 112) * 8 + (bid & 7);
  const int u = (bid % 112) >> 3;       // 0..13
  const int rb = u >> 1, bh = u & 1;
  if (c >= REPN) return;
  const int h0 = rb * 8;

  const int bloc = tid / 14;            // 0..18; >=16 inactive
  const int tw = tid - bloc * 14;       // 0..13
  const int w0 = tw * 4;
  const bool act = (bloc < 16);

  float wv[45];  // block-uniform -> SGPRs
  #pragma unroll
  for (int j = 0; j < 45; ++j) wv[j] = wsum[c * 45 + j];

  float A1 = 0.f, A2 = 0.f, A3 = 0.f, K_ = 0.f;
  if (PASS2) {
    A1 = stats2[c * 4 + 0]; A2 = stats2[c * 4 + 1];
    A3 = stats2[c * 4 + 2]; K_ = stats2[c * 4 + 3];
  }

  float s1 = 0, q1 = 0, s2 = 0, q2 = 0, s3 = 0, q3 = 0;

  if (act) {
    const int b = bh * 16 + bloc;
    const int src_c = rep_idx[c];
    const int ibase = (b * CIN + src_c) * IMG;
    const int vbase = ibase + w0 - 8;

    // window validity masks (window cols = w0-8+e)
    const float ma = (tw >= 2) ? 1.f : 0.f;   // e 0..3
    const float mb = (tw >= 1) ? 1.f : 0.f;   // e 4..7
    const float mc = (tw <= 12) ? 1.f : 0.f;  // e 12..15
    const float md = (tw <= 11) ? 1.f : 0.f;  // e 16..19

    const int s_lo = (rb == 0) ? 6 : 0;       // r = h0-6+s in [0,56)
    const int s_hi = (rb == 6) ? 13 : 21;

    float acc1[8][4] = {};
    float acc2[3][4] = {};
    float acc3[3][4] = {};
    float stash[7][4];   // PASS2: A2*l2 + A3*s until lora1 completes
    float xv[2][4];      // PASS2: residual prefetch, 2 iterations ahead

    float win[2][20];
    load_row20(win[0], in, vbase + (h0 - 6 + s_lo) * HW);  // s_lo&1 == 0

    #pragma unroll
    for (int s = 0; s < 22; ++s) {
      if (s >= s_lo && s <= s_hi) {
        if (s < s_hi)  // prefetch next row into the other buffer
          load_row20(win[(s + 1) & 1], in, vbase + (h0 - 5 + s) * HW);
        float* wc = win[s & 1];
        #pragma unroll
        for (int e = 0; e < 4; ++e) wc[e] *= ma;
        #pragma unroll
        for (int e = 4; e < 8; ++e) wc[e] *= mb;
        #pragma unroll
        for (int e = 12; e < 16; ++e) wc[e] *= mc;
        #pragma unroll
        for (int e = 16; e < 20; ++e) wc[e] *= md;

        // lora1 (15x3): vertical tap t = s - lr; x col -> e = dw+kw+7
        #pragma unroll
        for (int lr = 0; lr < 8; ++lr) {
          const int t = s - lr;
          if (t >= 0 && t < 15) {
            #pragma unroll
            for (int kw = 0; kw < 3; ++kw) {
              const float wgt = wv[3 * t + kw];
              #pragma unroll
              for (int dw = 0; dw < 4; ++dw)
                acc1[lr][dw] = fmaf(wc[dw + kw + 7], wgt, acc1[lr][dw]);
            }
          }
        }
        // lora2 (3x15) + small (3x3): kh = s - lr - 5
        #pragma unroll
        for (int lr = 0; lr < 8; ++lr) {
          const int kh = s - lr - 5;
          if (kh >= 0 && kh < 3) {
            #pragma unroll
            for (int T = 0; T < 15; ++T) {      // horiz tap -> e = dw+T+2
              const float wgt = wv[(T / 3) * 9 + kh * 3 + (T % 3)];
              #pragma unroll
              for (int dw = 0; dw < 4; ++dw)
                acc2[lr % 3][dw] = fmaf(wc[dw + T + 2], wgt, acc2[lr % 3][dw]);
            }
            #pragma unroll
            for (int kw = 0; kw < 3; ++kw) {
              const float wgt = wv[18 + kh * 3 + kw];
              #pragma unroll
              for (int dw = 0; dw < 4; ++dw)
                acc3[lr % 3][dw] = fmaf(wc[dw + kw + 7], wgt, acc3[lr % 3][dw]);
            }
          }
        }
      }

      // fold1 (lora1 row lr completes at s = lr+14) — before fold2: at equal s
      // they touch the same stash slot (read-then-write).
      if (s >= 14) {
        const int lr = s - 14;
        if (PASS2) {
          const int hh = h0 + lr;
          float4 o;
          o.x = fmaf(A1, acc1[lr][0], stash[lr % 7][0] + K_ + xv[lr & 1][0]);
          o.y = fmaf(A1, acc1[lr][1], stash[lr % 7][1] + K_ + xv[lr & 1][1]);
          o.z = fmaf(A1, acc1[lr][2], stash[lr % 7][2] + K_ + xv[lr & 1][2]);
          o.w = fmaf(A1, acc1[lr][3], stash[lr % 7][3] + K_ + xv[lr & 1][3]);
          *reinterpret_cast<float4*>(out + (size_t)(b * CIN + c) * IMG + hh * HW + w0) = o;
        } else {
          #pragma unroll
          for (int dw = 0; dw < 4; ++dw) {
            const float v = acc1[lr][dw];
            s1 += v; q1 = fmaf(v, v, q1);
          }
        }
      }
      // fold2 (lora2/small row lr completes at s = lr+7)
      if (s >= 7 && s <= 14) {
        const int lr = s - 7;
        #pragma unroll
        for (int dw = 0; dw < 4; ++dw) {
          const float v2 = acc2[lr % 3][dw], v3 = acc3[lr % 3][dw];
          if (PASS2) {
            stash[lr % 7][dw] = fmaf(A2, v2, A3 * v3);
          } else {
            s2 += v2; q2 = fmaf(v2, v2, q2);
            s3 += v3; q3 = fmaf(v3, v3, q3);
          }
          acc2[lr % 3][dw] = 0.f;
          acc3[lr % 3][dw] = 0.f;
        }
      }
      // PASS2 residual prefetch: row lr2 = s-12, consumed at s = lr2+14.
      // Placed after fold1 so the shared xv slot is free (read-then-write).
      if (PASS2 && s >= 12 && s <= 19) {
        const int lr2 = s - 12;
        const float4 x4 = *reinterpret_cast<const float4*>(
            in + ibase + (h0 + lr2) * HW + w0);
        xv[lr2 & 1][0] = x4.x; xv[lr2 & 1][1] = x4.y;
        xv[lr2 & 1][2] = x4.z; xv[lr2 & 1][3] = x4.w;
      }
    }
  }

  if (!PASS2) {
    __shared__ float red[4][6];
    #pragma unroll
    for (int off = 32; off > 0; off >>= 1) {
      s1 += __shfl_down(s1, off); q1 += __shfl_down(q1, off);
      s2 += __shfl_down(s2, off); q2 += __shfl_down(q2, off);
      s3 += __shfl_down(s3, off); q3 += __shfl_down(q3, off);
    }
    const int lane = tid & 63, wid = tid >> 6;
    if (lane == 0) {
      red[wid][0] = s1; red[wid][1] = q1; red[wid][2] = s2;
      red[wid][3] = q2; red[wid][4] = s3; red[wid][5] = q3;
    }
    __syncthreads();
    if (tid < 6)
      partial[(c * 14 + u) * 6 + tid] =
          red[0][tid] + red[1][tid] + red[2][tid] + red[3][tid];
  }
}

extern "C" __global__ void sw_prep(const float* __restrict__ w1, const float* __restrict__ w2,
                                   float* __restrict__ wsum) {
  int i = blockIdx.x * 256 + threadIdx.x;
  if (i < 8820) wsum[i] = w1[i] + w2[i];
}

extern "C" __global__ void sw_reduce(
    const float* __restrict__ partial,
    const float* __restrict__ g1, const float* __restrict__ b1,
    const float* __restrict__ g2, const float* __restrict__ b2,
    const float* __restrict__ g3, const float* __restrict__ b3,
    float* __restrict__ stats2) {
  const int c = blockIdx.x;
  const int tid = threadIdx.x;
  __shared__ float sm[6];
  if (tid < 6) {
    float s = 0;
    #pragma unroll
    for (int u = 0; u < 14; ++u) s += partial[(c * 14 + u) * 6 + tid];
    sm[tid] = s;
  }
  __syncthreads();
  if (tid == 0) {
    const float N = 100352.f;
    float m1 = sm[0] / N, v1 = sm[1] / N - m1 * m1;
    float m2 = sm[2] / N, v2 = sm[3] / N - m2 * m2;
    float m3 = sm[4] / N, v3 = sm[5] / N - m3 * m3;
    float A1 = g1[c] * rsqrtf(v1 + 1e-5f);
    float A2 = g2[c] * rsqrtf(v2 + 1e-5f);
    float A3 = g3[c] * rsqrtf(v3 + 1e-5f);
    float K = b1[c] + b2[c] + b3[c] - m1 * A1 - m2 * A2 - m3 * A3;
    stats2[c * 4 + 0] = A1; stats2[c * 4 + 1] = A2;
    stats2[c * 4 + 2] = A3; stats2[c * 4 + 3] = K;
  }
}

extern "C" void kernel_launch(void* const* d_in, const int* in_sizes, int n_in,
                              void* d_out, int out_size, void* d_ws, size_t ws_size,
                              hipStream_t stream) {
  const float* in  = (const float*)d_in[0];
  const float* w1  = (const float*)d_in[1];
  const float* w2  = (const float*)d_in[2];
  const float* g1  = (const float*)d_in[3];
  const float* b1  = (const float*)d_in[4];
  const float* g2  = (const float*)d_in[5];
  const float* b2  = (const float*)d_in[6];
  const float* g3  = (const float*)d_in[7];
  const float* b3  = (const float*)d_in[8];
  const int* ghost_idx = (const int*)d_in[9];
  const int* rep_idx   = (const int*)d_in[10];
  float* out = (float*)d_out;
  float* ws  = (float*)d_ws;

  float* wsum    = ws;          // 8820 floats
  float* stats2  = ws + 8832;   // 784 floats
  float* partial = ws + 9728;   // 196*14*6 = 16464 floats

  sw_prep<<<35, 256, 0, stream>>>(w1, w2, wsum);
  sw_conv<false><<<NCONVBLK, 256, 0, stream>>>(in, rep_idx, ghost_idx, wsum, stats2, partial, out);
  sw_reduce<<<196, 64, 0, stream>>>(partial, g1, b1, g2, b2, g3, b3, stats2);
  sw_conv<true><<<NCONVBLK + NGHOSTBLK, 256, 0, stream>>>(in, rep_idx, ghost_idx, wsum, stats2, partial, out);
}